// Round 1
// baseline (691.479 us; speedup 1.0000x reference)
//
#include <hip/hip_runtime.h>
#include <hip/hip_bf16.h>

// Encoder block: B=4 S=2048 D=1024 H=16 DH=64 DFF=4096
// Strategy (round 1, correctness-first):
//   f32 LN/softmax/GELU, bf16 MFMA (16x16x32) for all GEMMs + attention.
//   Weights transposed to B^T bf16 so both MFMA operands read contiguous
//   ds_read_b128 fragments. qkv packed GEMM (N=3072), flash attention with
//   online softmax, fused epilogues (bias/resid/GELU).

#define Bb_ 4
#define Ss_ 2048
#define Dd_ 1024
#define Hh_ 16
#define DHh_ 64
#define DFF_ 4096
#define Mm_ (Bb_*Ss_)   // 8192

typedef __bf16 bf16x8 __attribute__((ext_vector_type(8)));
typedef float f32x4 __attribute__((ext_vector_type(4)));

static __device__ __forceinline__ unsigned short f2bf(float f) {
  union { float f; unsigned u; } v; v.f = f;
  unsigned r = v.u + 0x7FFF + ((v.u >> 16) & 1);   // RNE
  return (unsigned short)(r >> 16);
}
static __device__ __forceinline__ float bf2f(unsigned short h) {
  union { unsigned u; float f; } v; v.u = ((unsigned)h) << 16;
  return v.f;
}

// ---------------- LayerNorm: f32 in -> bf16 out ----------------
__global__ __launch_bounds__(256) void ln_kernel(
    const float* __restrict__ x, const float* __restrict__ g,
    const float* __restrict__ bb, unsigned short* __restrict__ out)
{
  const int row = blockIdx.x;
  const int t = threadIdx.x;
  const float4 v = reinterpret_cast<const float4*>(x + (size_t)row * Dd_)[t];
  float s = v.x + v.y + v.z + v.w;
  float ss = v.x*v.x + v.y*v.y + v.z*v.z + v.w*v.w;
  #pragma unroll
  for (int o = 32; o; o >>= 1) { s += __shfl_down(s, o); ss += __shfl_down(ss, o); }
  __shared__ float red[8];
  if ((t & 63) == 0) { red[t >> 6] = s; red[4 + (t >> 6)] = ss; }
  __syncthreads();
  s = red[0] + red[1] + red[2] + red[3];
  ss = red[4] + red[5] + red[6] + red[7];
  const float mean = s * (1.f / Dd_);
  const float var = ss * (1.f / Dd_) - mean * mean;
  const float inv = rsqrtf(var + 1e-5f);
  const float4 gv = reinterpret_cast<const float4*>(g)[t];
  const float4 bv = reinterpret_cast<const float4*>(bb)[t];
  ushort4 o4;
  o4.x = f2bf((v.x - mean) * inv * gv.x + bv.x);
  o4.y = f2bf((v.y - mean) * inv * gv.y + bv.y);
  o4.z = f2bf((v.z - mean) * inv * gv.z + bv.z);
  o4.w = f2bf((v.w - mean) * inv * gv.w + bv.w);
  reinterpret_cast<ushort4*>(out + (size_t)row * Dd_)[t] = o4;
}

// ---------------- transpose + convert f32(KxN) -> bf16(NxK) ----------------
__global__ __launch_bounds__(256) void tconv_kernel(
    const float* __restrict__ src, unsigned short* __restrict__ dst, int K, int N)
{
  __shared__ float tile[32][33];
  const int bx = blockIdx.x, by = blockIdx.y;
  const int tx = threadIdx.x & 31, ty = threadIdx.x >> 5;
  #pragma unroll
  for (int i = 0; i < 4; i++)
    tile[ty + i * 8][tx] = src[(size_t)(by * 32 + ty + i * 8) * N + bx * 32 + tx];
  __syncthreads();
  #pragma unroll
  for (int i = 0; i < 4; i++)
    dst[(size_t)(bx * 32 + ty + i * 8) * K + by * 32 + tx] = f2bf(tile[tx][ty + i * 8]);
}

// ---------------- RoPE in-place on packed QKV (bf16) ----------------
__global__ __launch_bounds__(256) void rope_kernel(
    unsigned short* __restrict__ qkv, const float* __restrict__ fc)
{
  const int idx = blockIdx.x * 256 + threadIdx.x;   // 8192*1024 pairs
  const int row = idx >> 10;
  const int rem = idx & 1023;
  const int qk = rem >> 9;
  const int hd = (rem >> 5) & 15;
  const int i = rem & 31;
  const int s = row & (Ss_ - 1);
  const float c = fc[s * 64 + 2 * i], sn = fc[s * 64 + 2 * i + 1];
  const size_t p = (size_t)row * 3072 + qk * 1024 + hd * 64 + 2 * i;
  const float t0 = bf2f(qkv[p]), t1 = bf2f(qkv[p + 1]);
  qkv[p]     = f2bf(t0 * c - t1 * sn);
  qkv[p + 1] = f2bf(t0 * sn + t1 * c);
}

// ---------------- GEMM: A(MxK) bf16 row-major, BT(NxK) bf16 ----------------
// MODE 0: out bf16, plain          MODE 1: out f32 = acc + bias + resid
// MODE 2: out bf16 = gelu(acc+bias) MODE 3: out f32 = acc + bias + resid
template<int MODE>
__global__ __launch_bounds__(256) void gemm_kernel(
    const unsigned short* __restrict__ A,
    const unsigned short* __restrict__ BT,
    int K, int N,
    const float* __restrict__ bias,
    const float* __restrict__ resid,
    void* __restrict__ out)
{
  constexpr int LSTR = 48;  // LDS row stride (elems); 96B, 16B aligned
  __shared__ unsigned short Alds[128 * LSTR];
  __shared__ unsigned short Blds[128 * LSTR];
  const int t = threadIdx.x;
  const int bn = blockIdx.x, bm = blockIdx.y;
  const int wave = t >> 6, lane = t & 63;
  const int lq = lane >> 4, lr = lane & 15;
  const int wm = (wave >> 1) * 64, wn = (wave & 1) * 64;
  const int srow = t >> 2, squad = t & 3;

  const unsigned short* Ab = A + (size_t)(bm * 128) * K;
  const unsigned short* Bbp = BT + (size_t)(bn * 128) * K;

  f32x4 acc[4][4] = {};

  for (int kt = 0; kt < K; kt += 32) {
    __syncthreads();
    {
      const float4 a0 = *reinterpret_cast<const float4*>(Ab + (size_t)srow * K + kt + squad * 8);
      const float4 a1 = *reinterpret_cast<const float4*>(Ab + (size_t)(srow + 64) * K + kt + squad * 8);
      const float4 b0 = *reinterpret_cast<const float4*>(Bbp + (size_t)srow * K + kt + squad * 8);
      const float4 b1 = *reinterpret_cast<const float4*>(Bbp + (size_t)(srow + 64) * K + kt + squad * 8);
      *reinterpret_cast<float4*>(Alds + srow * LSTR + squad * 8) = a0;
      *reinterpret_cast<float4*>(Alds + (srow + 64) * LSTR + squad * 8) = a1;
      *reinterpret_cast<float4*>(Blds + srow * LSTR + squad * 8) = b0;
      *reinterpret_cast<float4*>(Blds + (srow + 64) * LSTR + squad * 8) = b1;
    }
    __syncthreads();
    bf16x8 af[4], bfr[4];
    #pragma unroll
    for (int i = 0; i < 4; i++)
      af[i] = *reinterpret_cast<const bf16x8*>(Alds + (wm + i * 16 + lr) * LSTR + lq * 8);
    #pragma unroll
    for (int j = 0; j < 4; j++)
      bfr[j] = *reinterpret_cast<const bf16x8*>(Blds + (wn + j * 16 + lr) * LSTR + lq * 8);
    #pragma unroll
    for (int i = 0; i < 4; i++)
      #pragma unroll
      for (int j = 0; j < 4; j++)
        acc[i][j] = __builtin_amdgcn_mfma_f32_16x16x32_bf16(af[i], bfr[j], acc[i][j], 0, 0, 0);
  }

  const int growbase = bm * 128 + wm + lq * 4;
  const int gcolbase = bn * 128 + wn + lr;
  #pragma unroll
  for (int j = 0; j < 4; j++) {
    const int col = gcolbase + j * 16;
    const float bj = (MODE != 0) ? bias[col] : 0.f;
    #pragma unroll
    for (int i = 0; i < 4; i++) {
      #pragma unroll
      for (int r = 0; r < 4; r++) {
        const int grow = growbase + i * 16 + r;
        const float v = acc[i][j][r];
        if (MODE == 0) {
          ((unsigned short*)out)[(size_t)grow * N + col] = f2bf(v);
        } else if (MODE == 1 || MODE == 3) {
          ((float*)out)[(size_t)grow * N + col] = v + bj + resid[(size_t)grow * N + col];
        } else {
          const float u = v + bj;
          const float gel = 0.5f * u * (1.f + erff(u * 0.70710678118654752f));
          ((unsigned short*)out)[(size_t)grow * N + col] = f2bf(gel);
        }
      }
    }
  }
}

// ---------------- Flash attention ----------------
// grid (S/64, H, B), block 256 = 4 waves; each wave owns 16 q-rows.
__global__ __launch_bounds__(256) void attn_kernel(
    const unsigned short* __restrict__ qkv, unsigned short* __restrict__ attout)
{
  constexpr int LST = 72;  // 144B row stride, 16B aligned, ~2-way banks
  __shared__ unsigned short Qs[64 * LST];
  __shared__ unsigned short Ks[64 * LST];
  __shared__ unsigned short Vt[64 * LST];  // transposed: [d][k]
  __shared__ unsigned short Ps[64 * LST];
  const int qt = blockIdx.x, h = blockIdx.y, b = blockIdx.z;
  const int t = threadIdx.x, wave = t >> 6, lane = t & 63;
  const int lq = lane >> 4, lr = lane & 15;

  const unsigned short* qbase = qkv + (size_t)(b * Ss_) * 3072 + h * 64;
  const unsigned short* kbase = qbase + 1024;
  const unsigned short* vbase = qbase + 2048;

  {  // stage Q tile (64x64)
    const unsigned short* src = qbase + (size_t)(qt * 64 + (t >> 2)) * 3072 + (t & 3) * 16;
    unsigned short* d = Qs + (t >> 2) * LST + (t & 3) * 16;
    *reinterpret_cast<float4*>(d)     = *reinterpret_cast<const float4*>(src);
    *reinterpret_cast<float4*>(d + 8) = *reinterpret_cast<const float4*>(src + 8);
  }
  __syncthreads();
  bf16x8 aq0 = *reinterpret_cast<const bf16x8*>(Qs + (wave * 16 + lr) * LST + lq * 8);
  bf16x8 aq1 = *reinterpret_cast<const bf16x8*>(Qs + (wave * 16 + lr) * LST + 32 + lq * 8);

  float mrow[4], lrow[4];
  f32x4 oacc[4] = {};
  #pragma unroll
  for (int r = 0; r < 4; r++) { mrow[r] = -1e30f; lrow[r] = 0.f; }

  for (int kt = 0; kt < Ss_ / 64; ++kt) {
    __syncthreads();
    {  // stage K tile
      const unsigned short* src = kbase + (size_t)(kt * 64 + (t >> 2)) * 3072 + (t & 3) * 16;
      unsigned short* d = Ks + (t >> 2) * LST + (t & 3) * 16;
      *reinterpret_cast<float4*>(d)     = *reinterpret_cast<const float4*>(src);
      *reinterpret_cast<float4*>(d + 8) = *reinterpret_cast<const float4*>(src + 8);
    }
    {  // stage V tile transposed
      const int k = t >> 2, dg = t & 3;
      const unsigned short* src = vbase + (size_t)(kt * 64 + k) * 3072 + dg * 16;
      #pragma unroll
      for (int e = 0; e < 16; e++)
        Vt[(dg * 16 + e) * LST + k] = src[e];
    }
    __syncthreads();

    // S = Q K^T (each wave: its 16 q-rows x 64 keys)
    f32x4 sacc[4];
    #pragma unroll
    for (int nf = 0; nf < 4; nf++) {
      bf16x8 kb0 = *reinterpret_cast<const bf16x8*>(Ks + (nf * 16 + lr) * LST + lq * 8);
      bf16x8 kb1 = *reinterpret_cast<const bf16x8*>(Ks + (nf * 16 + lr) * LST + 32 + lq * 8);
      f32x4 z = {};
      z = __builtin_amdgcn_mfma_f32_16x16x32_bf16(aq0, kb0, z, 0, 0, 0);
      z = __builtin_amdgcn_mfma_f32_16x16x32_bf16(aq1, kb1, z, 0, 0, 0);
      sacc[nf] = z;
    }
    // online softmax (rows live in 16-lane groups)
    #pragma unroll
    for (int r = 0; r < 4; r++) {
      float mx = fmaxf(fmaxf(sacc[0][r], sacc[1][r]), fmaxf(sacc[2][r], sacc[3][r]));
      #pragma unroll
      for (int o = 8; o; o >>= 1) mx = fmaxf(mx, __shfl_xor(mx, o));
      mx *= 0.125f;
      const float mn = fmaxf(mrow[r], mx);
      const float esc = expf(mrow[r] - mn);
      float rs = 0.f;
      #pragma unroll
      for (int nf = 0; nf < 4; nf++) {
        const float p = expf(sacc[nf][r] * 0.125f - mn);
        rs += p;
        Ps[(wave * 16 + lq * 4 + r) * LST + nf * 16 + lr] = f2bf(p);
      }
      #pragma unroll
      for (int o = 8; o; o >>= 1) rs += __shfl_xor(rs, o);
      lrow[r] = lrow[r] * esc + rs;
      mrow[r] = mn;
      #pragma unroll
      for (int nf = 0; nf < 4; nf++) oacc[nf][r] *= esc;
    }
    // PV (wave reads only its own Ps rows -> no extra barrier)
    bf16x8 pa0 = *reinterpret_cast<const bf16x8*>(Ps + (wave * 16 + lr) * LST + lq * 8);
    bf16x8 pa1 = *reinterpret_cast<const bf16x8*>(Ps + (wave * 16 + lr) * LST + 32 + lq * 8);
    #pragma unroll
    for (int nf = 0; nf < 4; nf++) {
      bf16x8 vb0 = *reinterpret_cast<const bf16x8*>(Vt + (nf * 16 + lr) * LST + lq * 8);
      bf16x8 vb1 = *reinterpret_cast<const bf16x8*>(Vt + (nf * 16 + lr) * LST + 32 + lq * 8);
      oacc[nf] = __builtin_amdgcn_mfma_f32_16x16x32_bf16(pa0, vb0, oacc[nf], 0, 0, 0);
      oacc[nf] = __builtin_amdgcn_mfma_f32_16x16x32_bf16(pa1, vb1, oacc[nf], 0, 0, 0);
    }
  }

  #pragma unroll
  for (int r = 0; r < 4; r++) {
    const float inv = 1.f / lrow[r];
    const int grow = b * Ss_ + qt * 64 + wave * 16 + lq * 4 + r;
    #pragma unroll
    for (int nf = 0; nf < 4; nf++)
      attout[(size_t)grow * Dd_ + h * 64 + nf * 16 + lr] = f2bf(oacc[nf][r] * inv);
  }
}

extern "C" void kernel_launch(void* const* d_in, const int* in_sizes, int n_in,
                              void* d_out, int out_size, void* d_ws, size_t ws_size,
                              hipStream_t stream) {
  const float* x      = (const float*)d_in[0];
  const float* fc     = (const float*)d_in[1];
  const float* wq     = (const float*)d_in[2];
  const float* wk     = (const float*)d_in[3];
  const float* wv     = (const float*)d_in[4];
  const float* w_proj = (const float*)d_in[5];
  const float* b_proj = (const float*)d_in[6];
  const float* w_ff1  = (const float*)d_in[7];
  const float* b_ff1  = (const float*)d_in[8];
  const float* w_ff2  = (const float*)d_in[9];
  const float* b_ff2  = (const float*)d_in[10];
  const float* ln1_g  = (const float*)d_in[11];
  const float* ln1_b  = (const float*)d_in[12];
  const float* ln2_g  = (const float*)d_in[13];
  const float* ln2_b  = (const float*)d_in[14];

  char* ws = (char*)d_ws;
  unsigned short* hb     = (unsigned short*)(ws);                  // 16 MB
  unsigned short* wqkvT  = (unsigned short*)(ws + 16777216ull);    // 6 MB
  unsigned short* wprojT = (unsigned short*)(ws + 23068672ull);    // 2 MB
  unsigned short* wff1T  = (unsigned short*)(ws + 25165824ull);    // 8 MB
  unsigned short* wff2T  = (unsigned short*)(ws + 33554432ull);    // 8 MB
  float*          x2     = (float*)(ws + 41943040ull);             // 32 MB
  unsigned short* attoutb= (unsigned short*)(ws + 75497472ull);    // 16 MB
  unsigned short* qkvb   = (unsigned short*)(ws + 92274688ull);    // 64 MB (qkv then ff1)
  unsigned short* ff1b   = qkvb;

  dim3 blk(256);

  // weights -> bf16 transposed
  tconv_kernel<<<dim3(32, 32), blk, 0, stream>>>(wq, wqkvT, 1024, 1024);
  tconv_kernel<<<dim3(32, 32), blk, 0, stream>>>(wk, wqkvT + 1024 * 1024, 1024, 1024);
  tconv_kernel<<<dim3(32, 32), blk, 0, stream>>>(wv, wqkvT + 2 * 1024 * 1024, 1024, 1024);
  tconv_kernel<<<dim3(32, 32), blk, 0, stream>>>(w_proj, wprojT, 1024, 1024);
  tconv_kernel<<<dim3(128, 32), blk, 0, stream>>>(w_ff1, wff1T, 1024, 4096);
  tconv_kernel<<<dim3(32, 128), blk, 0, stream>>>(w_ff2, wff2T, 4096, 1024);

  // LN1
  ln_kernel<<<8192, blk, 0, stream>>>(x, ln1_g, ln1_b, hb);
  // QKV gemm (M=8192, N=3072, K=1024) -> bf16
  gemm_kernel<0><<<dim3(24, 64), blk, 0, stream>>>(hb, wqkvT, 1024, 3072, nullptr, nullptr, qkvb);
  // RoPE on Q,K
  rope_kernel<<<32768, blk, 0, stream>>>(qkvb, fc);
  // attention
  attn_kernel<<<dim3(32, 16, 4), blk, 0, stream>>>(qkvb, attoutb);
  // proj + bias + residual -> x2 (f32)
  gemm_kernel<1><<<dim3(8, 64), blk, 0, stream>>>(attoutb, wprojT, 1024, 1024, b_proj, x, x2);
  // LN2
  ln_kernel<<<8192, blk, 0, stream>>>(x2, ln2_g, ln2_b, hb);
  // FF1 + bias + gelu -> bf16
  gemm_kernel<2><<<dim3(32, 64), blk, 0, stream>>>(hb, wff1T, 1024, 4096, b_ff1, nullptr, ff1b);
  // FF2 + bias + residual -> d_out (f32)
  gemm_kernel<3><<<dim3(8, 64), blk, 0, stream>>>(ff1b, wff2T, 4096, 1024, b_ff2, x2, (float*)d_out);
}

// Round 3
// 615.720 us; speedup vs baseline: 1.1230x; 1.1230x over previous
//
#include <hip/hip_runtime.h>
#include <hip/hip_bf16.h>

// Encoder block: B=4 S=2048 D=1024 H=16 DH=64 DFF=4096
// Round 3: identical to round 2 except the RoPE coverage fix
// (round 2 only rotated heads 0-7 of Q and K: rem&127 -> rem&255 etc.)

#define Bb_ 4
#define Ss_ 2048
#define Dd_ 1024
#define Hh_ 16
#define DFF_ 4096

typedef __bf16 bf16x8 __attribute__((ext_vector_type(8)));
typedef float f32x4 __attribute__((ext_vector_type(4)));

static __device__ __forceinline__ unsigned short f2bf(float f) {
  union { float f; unsigned u; } v; v.f = f;
  unsigned r = v.u + 0x7FFF + ((v.u >> 16) & 1);   // RNE
  return (unsigned short)(r >> 16);
}
static __device__ __forceinline__ float bf2f(unsigned short h) {
  union { unsigned u; float f; } v; v.u = ((unsigned)h) << 16;
  return v.f;
}

// async global->LDS, 16B per lane. LDS dest must be wave-uniform base + lane*16
// (all call sites satisfy this: lds byte offset is linear in threadIdx).
static __device__ __forceinline__ void gl16(const unsigned short* g, unsigned short* l) {
  __builtin_amdgcn_global_load_lds(
      (const __attribute__((address_space(1))) void*)g,
      (__attribute__((address_space(3))) void*)l, 16, 0, 0);
}

// ---------------- LayerNorm: f32 in -> bf16 out ----------------
__global__ __launch_bounds__(256) void ln_kernel(
    const float* __restrict__ x, const float* __restrict__ g,
    const float* __restrict__ bb, unsigned short* __restrict__ out)
{
  const int row = blockIdx.x;
  const int t = threadIdx.x;
  const float4 v = reinterpret_cast<const float4*>(x + (size_t)row * Dd_)[t];
  float s = v.x + v.y + v.z + v.w;
  float ss = v.x*v.x + v.y*v.y + v.z*v.z + v.w*v.w;
  #pragma unroll
  for (int o = 32; o; o >>= 1) { s += __shfl_down(s, o); ss += __shfl_down(ss, o); }
  __shared__ float red[8];
  if ((t & 63) == 0) { red[t >> 6] = s; red[4 + (t >> 6)] = ss; }
  __syncthreads();
  s = red[0] + red[1] + red[2] + red[3];
  ss = red[4] + red[5] + red[6] + red[7];
  const float mean = s * (1.f / Dd_);
  const float var = ss * (1.f / Dd_) - mean * mean;
  const float inv = rsqrtf(var + 1e-5f);
  const float4 gv = reinterpret_cast<const float4*>(g)[t];
  const float4 bv = reinterpret_cast<const float4*>(bb)[t];
  ushort4 o4;
  o4.x = f2bf((v.x - mean) * inv * gv.x + bv.x);
  o4.y = f2bf((v.y - mean) * inv * gv.y + bv.y);
  o4.z = f2bf((v.z - mean) * inv * gv.z + bv.z);
  o4.w = f2bf((v.w - mean) * inv * gv.w + bv.w);
  reinterpret_cast<ushort4*>(out + (size_t)row * Dd_)[t] = o4;
}

// ---------------- transpose + convert f32(KxN) -> bf16(NxK) ----------------
__global__ __launch_bounds__(256) void tconv_kernel(
    const float* __restrict__ src, unsigned short* __restrict__ dst, int K, int N)
{
  __shared__ float tile[32][33];
  const int bx = blockIdx.x, by = blockIdx.y;
  const int tx = threadIdx.x & 31, ty = threadIdx.x >> 5;
  #pragma unroll
  for (int i = 0; i < 4; i++)
    tile[ty + i * 8][tx] = src[(size_t)(by * 32 + ty + i * 8) * N + bx * 32 + tx];
  __syncthreads();
  #pragma unroll
  for (int i = 0; i < 4; i++)
    dst[(size_t)(bx * 32 + ty + i * 8) * K + by * 32 + tx] = f2bf(tile[tx][ty + i * 8]);
}

// ---------------- RoPE in-place on packed QKV (bf16), 16B/lane ----------------
__global__ __launch_bounds__(256) void rope_kernel(
    unsigned short* __restrict__ qkv, const float* __restrict__ fc)
{
  const int c = blockIdx.x * 256 + threadIdx.x;  // 2,097,152 chunks of 8 elems
  const int row = c >> 8;        // 256 chunks per row (Q:128, K:128)
  const int rem = c & 255;
  const int qk = rem >> 7;       // 0=Q, 1=K
  const int e8 = rem & 127;      // 8-elem chunk within the 1024-elem half
  const int s = row & (Ss_ - 1);
  const float4 f0 = *reinterpret_cast<const float4*>(fc + s * 64 + (e8 & 7) * 8);
  const float4 f1 = *reinterpret_cast<const float4*>(fc + s * 64 + (e8 & 7) * 8 + 4);
  unsigned short* p = qkv + (size_t)row * 3072 + qk * 1024 + e8 * 8;
  uint4 dv = *reinterpret_cast<const uint4*>(p);
  unsigned u[4] = {dv.x, dv.y, dv.z, dv.w};
  const float cs[8] = {f0.x, f0.y, f0.z, f0.w, f1.x, f1.y, f1.z, f1.w};
  #pragma unroll
  for (int j = 0; j < 4; j++) {
    const float t0 = bf2f((unsigned short)(u[j] & 0xffff));
    const float t1 = bf2f((unsigned short)(u[j] >> 16));
    const float cj = cs[2 * j], sj = cs[2 * j + 1];
    const float o0 = t0 * cj - t1 * sj;
    const float o1 = t0 * sj + t1 * cj;
    u[j] = (unsigned)f2bf(o0) | ((unsigned)f2bf(o1) << 16);
  }
  uint4 ov; ov.x = u[0]; ov.y = u[1]; ov.z = u[2]; ov.w = u[3];
  *reinterpret_cast<uint4*>(p) = ov;
}

// ---------------- V transpose: qkv V-slice -> vt[(b*16+h)*64 + d][2048] ----------------
__global__ __launch_bounds__(256) void vtrans_kernel(
    const unsigned short* __restrict__ qkv, unsigned short* __restrict__ vt)
{
  __shared__ unsigned short tile[64 * 64];
  const int st = blockIdx.x, h = blockIdx.y, b = blockIdx.z;
  const int t = threadIdx.x;
  const unsigned short* src = qkv + (size_t)(b * Ss_ + st * 64) * 3072 + 2048 + h * 64;
  {
    const int s = t >> 2;
    const int v = (s >> 3) & 7;
    #pragma unroll
    for (int j = 0; j < 2; j++) {
      const int col8 = (t & 3) * 2 + j;
      const uint4 d = *reinterpret_cast<const uint4*>(src + (size_t)s * 3072 + col8 * 8);
      *reinterpret_cast<uint4*>(&tile[s * 64 + ((col8 * 8) ^ (v * 8))]) = d;
    }
  }
  __syncthreads();
  unsigned short* dst = vt + (size_t)((b * 16 + h) * 64) * Ss_ + st * 64;
  #pragma unroll
  for (int it = 0; it < 2; it++) {
    const int c = t + it * 256;
    const int d = c >> 3, s8 = c & 7;
    unsigned short o[8];
    #pragma unroll
    for (int j = 0; j < 8; j++) {
      const int s = s8 * 8 + j;
      o[j] = tile[s * 64 + (d ^ (((s >> 3) & 7) * 8))];
    }
    *reinterpret_cast<uint4*>(dst + (size_t)d * Ss_ + s8 * 8) = *reinterpret_cast<uint4*>(o);
  }
}

// ---------------- GEMM (m97 structure): A(MxK), BT(NxK) bf16; BK=64 ----------------
// MODE 0: out bf16  | 1: f32 = acc+bias+resid | 2: bf16 = gelu(acc+bias) | 3: same as 1
template<int MODE>
__global__ __launch_bounds__(256) void gemm_kernel(
    const unsigned short* __restrict__ A,
    const unsigned short* __restrict__ BT,
    int K, int N,
    const float* __restrict__ bias,
    const float* __restrict__ resid,
    void* __restrict__ out)
{
  __shared__ unsigned short Alds[128 * 64];
  __shared__ unsigned short Blds[128 * 64];
  const int t = threadIdx.x;
  const int bn = blockIdx.x, bm = blockIdx.y;
  const int w = t >> 6, lane = t & 63;
  const int lq = lane >> 4, lr = lane & 15;
  const int wm = (w >> 1) * 64, wn = (w & 1) * 64;
  const int srow = t >> 3, sg8 = t & 7;

  const unsigned short* Ab = A + (size_t)(bm * 128) * K;
  const unsigned short* Bb = BT + (size_t)(bn * 128) * K;

  f32x4 acc[4][4] = {};

  for (int kt = 0; kt < K; kt += 64) {
    __syncthreads();
    #pragma unroll
    for (int i = 0; i < 4; i++) {
      const int row = i * 32 + srow;
      const int g8 = sg8 ^ (row & 7);          // inverse source swizzle
      gl16(Ab + (size_t)row * K + kt + g8 * 8, &Alds[row * 64 + sg8 * 8]);
      gl16(Bb + (size_t)row * K + kt + g8 * 8, &Blds[row * 64 + sg8 * 8]);
    }
    __syncthreads();
    #pragma unroll
    for (int kc = 0; kc < 2; kc++) {
      bf16x8 af[4], bfr[4];
      const int cofs = kc * 32 + lq * 8;
      const int swz = (lr & 7) * 8;
      #pragma unroll
      for (int i = 0; i < 4; i++) {
        af[i]  = *reinterpret_cast<const bf16x8*>(&Alds[(wm + i * 16 + lr) * 64 + (cofs ^ swz)]);
        bfr[i] = *reinterpret_cast<const bf16x8*>(&Blds[(wn + i * 16 + lr) * 64 + (cofs ^ swz)]);
      }
      #pragma unroll
      for (int i = 0; i < 4; i++)
        #pragma unroll
        for (int j = 0; j < 4; j++)
          acc[i][j] = __builtin_amdgcn_mfma_f32_16x16x32_bf16(af[i], bfr[j], acc[i][j], 0, 0, 0);
    }
  }

  const int growbase = bm * 128 + wm + lq * 4;
  const int gcolbase = bn * 128 + wn + lr;
  #pragma unroll
  for (int j = 0; j < 4; j++) {
    const int col = gcolbase + j * 16;
    const float bj = (MODE != 0) ? bias[col] : 0.f;
    #pragma unroll
    for (int i = 0; i < 4; i++) {
      #pragma unroll
      for (int r = 0; r < 4; r++) {
        const int grow = growbase + i * 16 + r;
        const float v = acc[i][j][r];
        if (MODE == 0) {
          ((unsigned short*)out)[(size_t)grow * N + col] = f2bf(v);
        } else if (MODE == 1 || MODE == 3) {
          ((float*)out)[(size_t)grow * N + col] = v + bj + resid[(size_t)grow * N + col];
        } else {
          const float u = v + bj;
          const float gel = 0.5f * u * (1.f + erff(u * 0.70710678118654752f));
          ((unsigned short*)out)[(size_t)grow * N + col] = f2bf(gel);
        }
      }
    }
  }
}

// ---------------- Flash attention v2 ----------------
// grid (S/128, H, B), 256 thr = 4 waves; wave owns 32 q-rows. K/V^T staged via
// global_load_lds into linear LDS (source-swizzled), double-buffered, 1 barrier/tile.
__global__ __launch_bounds__(256) void attn_kernel(
    const unsigned short* __restrict__ qkv,   // [8192][3072] (Q,K rope'd)
    const unsigned short* __restrict__ vt,    // [(b*16+h)*64 + d][2048]
    unsigned short* __restrict__ attout)      // [8192][1024]
{
  __shared__ unsigned short Ks[2][64 * 64];
  __shared__ unsigned short Vs[2][64 * 64];
  __shared__ unsigned short Ps[128 * 64];
  const int qt = blockIdx.x, h = blockIdx.y, b = blockIdx.z;
  const int t = threadIdx.x, w = t >> 6, lane = t & 63;
  const int lq = lane >> 4, lr = lane & 15;
  const int srow = t >> 3, sg8 = t & 7;

  const unsigned short* kg = qkv + (size_t)(b * Ss_) * 3072 + 1024 + h * 64;
  const unsigned short* vg = vt + (size_t)((b * 16 + h) * 64) * Ss_;

  // Q fragments: direct global->reg (rows w*32+mt*16+lr, 16B contiguous)
  bf16x8 aq[2][2];
  {
    const unsigned short* qg = qkv + (size_t)(b * Ss_ + qt * 128) * 3072 + h * 64;
    #pragma unroll
    for (int mt = 0; mt < 2; mt++)
      #pragma unroll
      for (int kc = 0; kc < 2; kc++)
        aq[mt][kc] = *reinterpret_cast<const bf16x8*>(
            qg + (size_t)(w * 32 + mt * 16 + lr) * 3072 + kc * 32 + lq * 8);
  }

  float mrow[2][4], lsum[2][4];
  f32x4 oacc[2][4] = {};
  #pragma unroll
  for (int mt = 0; mt < 2; mt++)
    #pragma unroll
    for (int r = 0; r < 4; r++) { mrow[mt][r] = -1e30f; lsum[mt][r] = 0.f; }

  const int g8s0 = sg8 ^ ((srow)      & 7);
  const int g8s1 = sg8 ^ ((srow + 32) & 7);

  // prologue: stage tile 0
  {
    gl16(kg + (size_t)(srow)      * 3072 + g8s0 * 8, &Ks[0][(srow)      * 64 + sg8 * 8]);
    gl16(kg + (size_t)(srow + 32) * 3072 + g8s1 * 8, &Ks[0][(srow + 32) * 64 + sg8 * 8]);
    gl16(vg + (size_t)(srow)      * Ss_  + g8s0 * 8, &Vs[0][(srow)      * 64 + sg8 * 8]);
    gl16(vg + (size_t)(srow + 32) * Ss_  + g8s1 * 8, &Vs[0][(srow + 32) * 64 + sg8 * 8]);
  }
  __syncthreads();

  const float SC2 = 0.125f * 1.44269504088896f;  // 1/sqrt(DH) * log2(e)

  for (int kt = 0; kt < Ss_ / 64; ++kt) {
    const int cur = kt & 1;
    if (kt < Ss_ / 64 - 1) {  // prefetch next tile into other buffer
      const int nb = cur ^ 1;
      const size_t ko = (size_t)((kt + 1) * 64);
      gl16(kg + (ko + srow)      * 3072 + g8s0 * 8, &Ks[nb][(srow)      * 64 + sg8 * 8]);
      gl16(kg + (ko + srow + 32) * 3072 + g8s1 * 8, &Ks[nb][(srow + 32) * 64 + sg8 * 8]);
      gl16(vg + (size_t)(srow)      * Ss_ + (kt + 1) * 64 + g8s0 * 8, &Vs[nb][(srow)      * 64 + sg8 * 8]);
      gl16(vg + (size_t)(srow + 32) * Ss_ + (kt + 1) * 64 + g8s1 * 8, &Vs[nb][(srow + 32) * 64 + sg8 * 8]);
    }

    // S = Q K^T
    f32x4 sacc[2][4] = {};
    #pragma unroll
    for (int kc = 0; kc < 2; kc++) {
      const int cofs = kc * 32 + lq * 8;
      const int swz = (lr & 7) * 8;
      bf16x8 kb[4];
      #pragma unroll
      for (int nf = 0; nf < 4; nf++)
        kb[nf] = *reinterpret_cast<const bf16x8*>(&Ks[cur][(nf * 16 + lr) * 64 + (cofs ^ swz)]);
      #pragma unroll
      for (int mt = 0; mt < 2; mt++)
        #pragma unroll
        for (int nf = 0; nf < 4; nf++)
          sacc[mt][nf] = __builtin_amdgcn_mfma_f32_16x16x32_bf16(aq[mt][kc], kb[nf], sacc[mt][nf], 0, 0, 0);
    }

    // online softmax in log2 domain; P -> Ps (swizzled)
    #pragma unroll
    for (int mt = 0; mt < 2; mt++) {
      #pragma unroll
      for (int r = 0; r < 4; r++) {
        const float s0 = sacc[mt][0][r], s1 = sacc[mt][1][r];
        const float s2 = sacc[mt][2][r], s3 = sacc[mt][3][r];
        float mx = fmaxf(fmaxf(s0, s1), fmaxf(s2, s3));
        #pragma unroll
        for (int o = 8; o; o >>= 1) mx = fmaxf(mx, __shfl_xor(mx, o));
        const float m2 = mx * SC2;
        const float mn = fmaxf(mrow[mt][r], m2);
        const float esc = exp2f(mrow[mt][r] - mn);
        const float p0 = exp2f(s0 * SC2 - mn);
        const float p1 = exp2f(s1 * SC2 - mn);
        const float p2 = exp2f(s2 * SC2 - mn);
        const float p3 = exp2f(s3 * SC2 - mn);
        const int row = w * 32 + mt * 16 + lq * 4 + r;
        const int vsw = ((row >> 2) & 7) * 8;
        Ps[row * 64 + ((0 * 16 + lr) ^ vsw)] = f2bf(p0);
        Ps[row * 64 + ((1 * 16 + lr) ^ vsw)] = f2bf(p1);
        Ps[row * 64 + ((2 * 16 + lr) ^ vsw)] = f2bf(p2);
        Ps[row * 64 + ((3 * 16 + lr) ^ vsw)] = f2bf(p3);
        float rs = ((p0 + p1) + (p2 + p3));
        #pragma unroll
        for (int o = 8; o; o >>= 1) rs += __shfl_xor(rs, o);
        lsum[mt][r] = lsum[mt][r] * esc + rs;
        mrow[mt][r] = mn;
        #pragma unroll
        for (int nf = 0; nf < 4; nf++) oacc[mt][nf][r] *= esc;
      }
    }

    // O += P V  (Ps rows are wave-local: no barrier needed)
    #pragma unroll
    for (int kc = 0; kc < 2; kc++) {
      const int cofs = kc * 32 + lq * 8;
      const int swz = (lr & 7) * 8;
      bf16x8 pa[2], vb[4];
      #pragma unroll
      for (int mt = 0; mt < 2; mt++) {
        const int row = w * 32 + mt * 16 + lr;
        pa[mt] = *reinterpret_cast<const bf16x8*>(&Ps[row * 64 + (cofs ^ (((row >> 2) & 7) * 8))]);
      }
      #pragma unroll
      for (int nf = 0; nf < 4; nf++)
        vb[nf] = *reinterpret_cast<const bf16x8*>(&Vs[cur][(nf * 16 + lr) * 64 + (cofs ^ swz)]);
      #pragma unroll
      for (int mt = 0; mt < 2; mt++)
        #pragma unroll
        for (int nf = 0; nf < 4; nf++)
          oacc[mt][nf] = __builtin_amdgcn_mfma_f32_16x16x32_bf16(pa[mt], vb[nf], oacc[mt][nf], 0, 0, 0);
    }

    __syncthreads();  // drains prefetch (vmcnt) + all waves done with buf[cur]
  }

  #pragma unroll
  for (int mt = 0; mt < 2; mt++) {
    #pragma unroll
    for (int r = 0; r < 4; r++) {
      const float inv = 1.f / lsum[mt][r];
      const int grow = b * Ss_ + qt * 128 + w * 32 + mt * 16 + lq * 4 + r;
      #pragma unroll
      for (int nf = 0; nf < 4; nf++)
        attout[(size_t)grow * Dd_ + h * 64 + nf * 16 + lr] = f2bf(oacc[mt][nf][r] * inv);
    }
  }
}

extern "C" void kernel_launch(void* const* d_in, const int* in_sizes, int n_in,
                              void* d_out, int out_size, void* d_ws, size_t ws_size,
                              hipStream_t stream) {
  const float* x      = (const float*)d_in[0];
  const float* fc     = (const float*)d_in[1];
  const float* wq     = (const float*)d_in[2];
  const float* wk     = (const float*)d_in[3];
  const float* wv     = (const float*)d_in[4];
  const float* w_proj = (const float*)d_in[5];
  const float* b_proj = (const float*)d_in[6];
  const float* w_ff1  = (const float*)d_in[7];
  const float* b_ff1  = (const float*)d_in[8];
  const float* w_ff2  = (const float*)d_in[9];
  const float* b_ff2  = (const float*)d_in[10];
  const float* ln1_g  = (const float*)d_in[11];
  const float* ln1_b  = (const float*)d_in[12];
  const float* ln2_g  = (const float*)d_in[13];
  const float* ln2_b  = (const float*)d_in[14];

  char* ws = (char*)d_ws;
  unsigned short* hb     = (unsigned short*)(ws);                  // 16 MB
  unsigned short* wqkvT  = (unsigned short*)(ws + 16777216ull);    // 6 MB
  unsigned short* wprojT = (unsigned short*)(ws + 23068672ull);    // 2 MB
  unsigned short* wff1T  = (unsigned short*)(ws + 25165824ull);    // 8 MB
  unsigned short* wff2T  = (unsigned short*)(ws + 33554432ull);    // 8 MB
  float*          x2     = (float*)(ws + 41943040ull);             // 32 MB (aliases vtb)
  unsigned short* vtb    = (unsigned short*)(ws + 41943040ull);    // 16 MB, dead before x2 written
  unsigned short* attoutb= (unsigned short*)(ws + 75497472ull);    // 16 MB
  unsigned short* qkvb   = (unsigned short*)(ws + 92274688ull);    // 64 MB (qkv then ff1)
  unsigned short* ff1b   = qkvb;

  dim3 blk(256);

  // weights -> bf16 transposed
  tconv_kernel<<<dim3(32, 32), blk, 0, stream>>>(wq, wqkvT, 1024, 1024);
  tconv_kernel<<<dim3(32, 32), blk, 0, stream>>>(wk, wqkvT + 1024 * 1024, 1024, 1024);
  tconv_kernel<<<dim3(32, 32), blk, 0, stream>>>(wv, wqkvT + 2 * 1024 * 1024, 1024, 1024);
  tconv_kernel<<<dim3(32, 32), blk, 0, stream>>>(w_proj, wprojT, 1024, 1024);
  tconv_kernel<<<dim3(128, 32), blk, 0, stream>>>(w_ff1, wff1T, 1024, 4096);
  tconv_kernel<<<dim3(32, 128), blk, 0, stream>>>(w_ff2, wff2T, 4096, 1024);

  // LN1
  ln_kernel<<<8192, blk, 0, stream>>>(x, ln1_g, ln1_b, hb);
  // QKV gemm (M=8192, N=3072, K=1024) -> bf16
  gemm_kernel<0><<<dim3(24, 64), blk, 0, stream>>>(hb, wqkvT, 1024, 3072, nullptr, nullptr, qkvb);
  // RoPE on Q,K
  rope_kernel<<<8192, blk, 0, stream>>>(qkvb, fc);
  // V transpose -> vtb
  vtrans_kernel<<<dim3(32, 16, 4), blk, 0, stream>>>(qkvb, vtb);
  // attention
  attn_kernel<<<dim3(16, 16, 4), blk, 0, stream>>>(qkvb, vtb, attoutb);
  // proj + bias + residual -> x2 (f32)
  gemm_kernel<1><<<dim3(8, 64), blk, 0, stream>>>(attoutb, wprojT, 1024, 1024, b_proj, x, x2);
  // LN2
  ln_kernel<<<8192, blk, 0, stream>>>(x2, ln2_g, ln2_b, hb);
  // FF1 + bias + gelu -> bf16
  gemm_kernel<2><<<dim3(32, 64), blk, 0, stream>>>(hb, wff1T, 1024, 4096, b_ff1, nullptr, ff1b);
  // FF2 + bias + residual -> d_out (f32)
  gemm_kernel<3><<<dim3(8, 64), blk, 0, stream>>>(ff1b, wff2T, 4096, 1024, b_ff2, x2, (float*)d_out);
}

// Round 4
// 479.877 us; speedup vs baseline: 1.4409x; 1.2831x over previous
//
#include <hip/hip_runtime.h>
#include <hip/hip_bf16.h>

// Encoder block: B=4 S=2048 D=1024 H=16 DH=64 DFF=4096
// Round 4: attention softmax de-serialization:
//   - no-max softmax (shift-invariance, c=0; inputs bounded ~6 sigma << f32 range)
//   - row-sum via ones-MFMA accumulator (no cross-lane reduces at all)
//   - swapped QK^T (mfma(K,Q)) so lanes hold consecutive keys -> cvt_pk + b64 P writes
//   GEMM: BN=64 tile variant for proj/FF2 (1024 blocks instead of 512).

#define Bb_ 4
#define Ss_ 2048
#define Dd_ 1024
#define Hh_ 16
#define DFF_ 4096

typedef __bf16 bf16x8 __attribute__((ext_vector_type(8)));
typedef float f32x4 __attribute__((ext_vector_type(4)));

static __device__ __forceinline__ unsigned short f2bf(float f) {
  union { float f; unsigned u; } v; v.f = f;
  unsigned r = v.u + 0x7FFF + ((v.u >> 16) & 1);   // RNE
  return (unsigned short)(r >> 16);
}
static __device__ __forceinline__ float bf2f(unsigned short h) {
  union { unsigned u; float f; } v; v.u = ((unsigned)h) << 16;
  return v.f;
}
static __device__ __forceinline__ unsigned cvt_pk_bf16(float lo, float hi) {
  unsigned r;
  asm("v_cvt_pk_bf16_f32 %0, %1, %2" : "=v"(r) : "v"(lo), "v"(hi));
  return r;
}

// async global->LDS, 16B per lane. LDS dest must be wave-uniform base + lane*16.
static __device__ __forceinline__ void gl16(const unsigned short* g, unsigned short* l) {
  __builtin_amdgcn_global_load_lds(
      (const __attribute__((address_space(1))) void*)g,
      (__attribute__((address_space(3))) void*)l, 16, 0, 0);
}

// ---------------- LayerNorm: f32 in -> bf16 out ----------------
__global__ __launch_bounds__(256) void ln_kernel(
    const float* __restrict__ x, const float* __restrict__ g,
    const float* __restrict__ bb, unsigned short* __restrict__ out)
{
  const int row = blockIdx.x;
  const int t = threadIdx.x;
  const float4 v = reinterpret_cast<const float4*>(x + (size_t)row * Dd_)[t];
  float s = v.x + v.y + v.z + v.w;
  float ss = v.x*v.x + v.y*v.y + v.z*v.z + v.w*v.w;
  #pragma unroll
  for (int o = 32; o; o >>= 1) { s += __shfl_down(s, o); ss += __shfl_down(ss, o); }
  __shared__ float red[8];
  if ((t & 63) == 0) { red[t >> 6] = s; red[4 + (t >> 6)] = ss; }
  __syncthreads();
  s = red[0] + red[1] + red[2] + red[3];
  ss = red[4] + red[5] + red[6] + red[7];
  const float mean = s * (1.f / Dd_);
  const float var = ss * (1.f / Dd_) - mean * mean;
  const float inv = rsqrtf(var + 1e-5f);
  const float4 gv = reinterpret_cast<const float4*>(g)[t];
  const float4 bv = reinterpret_cast<const float4*>(bb)[t];
  ushort4 o4;
  o4.x = f2bf((v.x - mean) * inv * gv.x + bv.x);
  o4.y = f2bf((v.y - mean) * inv * gv.y + bv.y);
  o4.z = f2bf((v.z - mean) * inv * gv.z + bv.z);
  o4.w = f2bf((v.w - mean) * inv * gv.w + bv.w);
  reinterpret_cast<ushort4*>(out + (size_t)row * Dd_)[t] = o4;
}

// ---------------- transpose + convert f32(KxN) -> bf16(NxK) ----------------
__global__ __launch_bounds__(256) void tconv_kernel(
    const float* __restrict__ src, unsigned short* __restrict__ dst, int K, int N)
{
  __shared__ float tile[32][33];
  const int bx = blockIdx.x, by = blockIdx.y;
  const int tx = threadIdx.x & 31, ty = threadIdx.x >> 5;
  #pragma unroll
  for (int i = 0; i < 4; i++)
    tile[ty + i * 8][tx] = src[(size_t)(by * 32 + ty + i * 8) * N + bx * 32 + tx];
  __syncthreads();
  #pragma unroll
  for (int i = 0; i < 4; i++)
    dst[(size_t)(bx * 32 + ty + i * 8) * K + by * 32 + tx] = f2bf(tile[tx][ty + i * 8]);
}

// ---------------- RoPE in-place on packed QKV (bf16), 16B/lane ----------------
__global__ __launch_bounds__(256) void rope_kernel(
    unsigned short* __restrict__ qkv, const float* __restrict__ fc)
{
  const int c = blockIdx.x * 256 + threadIdx.x;  // 2,097,152 chunks of 8 elems
  const int row = c >> 8;        // 256 chunks per row (Q:128, K:128)
  const int rem = c & 255;
  const int qk = rem >> 7;       // 0=Q, 1=K
  const int e8 = rem & 127;      // 8-elem chunk within the 1024-elem half
  const int s = row & (Ss_ - 1);
  const float4 f0 = *reinterpret_cast<const float4*>(fc + s * 64 + (e8 & 7) * 8);
  const float4 f1 = *reinterpret_cast<const float4*>(fc + s * 64 + (e8 & 7) * 8 + 4);
  unsigned short* p = qkv + (size_t)row * 3072 + qk * 1024 + e8 * 8;
  uint4 dv = *reinterpret_cast<const uint4*>(p);
  unsigned u[4] = {dv.x, dv.y, dv.z, dv.w};
  const float cs[8] = {f0.x, f0.y, f0.z, f0.w, f1.x, f1.y, f1.z, f1.w};
  #pragma unroll
  for (int j = 0; j < 4; j++) {
    const float t0 = bf2f((unsigned short)(u[j] & 0xffff));
    const float t1 = bf2f((unsigned short)(u[j] >> 16));
    const float cj = cs[2 * j], sj = cs[2 * j + 1];
    const float o0 = t0 * cj - t1 * sj;
    const float o1 = t0 * sj + t1 * cj;
    u[j] = (unsigned)f2bf(o0) | ((unsigned)f2bf(o1) << 16);
  }
  uint4 ov; ov.x = u[0]; ov.y = u[1]; ov.z = u[2]; ov.w = u[3];
  *reinterpret_cast<uint4*>(p) = ov;
}

// ---------------- V transpose: qkv V-slice -> vt[(b*16+h)*64 + d][2048] ----------------
__global__ __launch_bounds__(256) void vtrans_kernel(
    const unsigned short* __restrict__ qkv, unsigned short* __restrict__ vt)
{
  __shared__ unsigned short tile[64 * 64];
  const int st = blockIdx.x, h = blockIdx.y, b = blockIdx.z;
  const int t = threadIdx.x;
  const unsigned short* src = qkv + (size_t)(b * Ss_ + st * 64) * 3072 + 2048 + h * 64;
  {
    const int s = t >> 2;
    const int v = (s >> 3) & 7;
    #pragma unroll
    for (int j = 0; j < 2; j++) {
      const int col8 = (t & 3) * 2 + j;
      const uint4 d = *reinterpret_cast<const uint4*>(src + (size_t)s * 3072 + col8 * 8);
      *reinterpret_cast<uint4*>(&tile[s * 64 + ((col8 * 8) ^ (v * 8))]) = d;
    }
  }
  __syncthreads();
  unsigned short* dst = vt + (size_t)((b * 16 + h) * 64) * Ss_ + st * 64;
  #pragma unroll
  for (int it = 0; it < 2; it++) {
    const int c = t + it * 256;
    const int d = c >> 3, s8 = c & 7;
    unsigned short o[8];
    #pragma unroll
    for (int j = 0; j < 8; j++) {
      const int s = s8 * 8 + j;
      o[j] = tile[s * 64 + (d ^ (((s >> 3) & 7) * 8))];
    }
    *reinterpret_cast<uint4*>(dst + (size_t)d * Ss_ + s8 * 8) = *reinterpret_cast<uint4*>(o);
  }
}

// ---------------- GEMM (m97 structure): A(MxK), BT(NxK) bf16; BK=64 ----------------
// Tile 128 x BN (BN = 128 or 64), 4 waves as 2x2 of 64 x BN/2.
// MODE 0: out bf16 | 1: f32 = acc+bias+resid | 2: bf16 = gelu(acc+bias) | 3: same as 1
template<int MODE, int BN>
__global__ __launch_bounds__(256) void gemm_kernel(
    const unsigned short* __restrict__ A,
    const unsigned short* __restrict__ BT,
    int K, int N,
    const float* __restrict__ bias,
    const float* __restrict__ resid,
    void* __restrict__ out)
{
  constexpr int NF = BN / 32;   // n-fragments per wave
  __shared__ unsigned short Alds[128 * 64];
  __shared__ unsigned short Blds[BN * 64];
  const int t = threadIdx.x;
  const int bn = blockIdx.x, bm = blockIdx.y;
  const int w = t >> 6, lane = t & 63;
  const int lq = lane >> 4, lr = lane & 15;
  const int wm = (w >> 1) * 64, wn = (w & 1) * (BN / 2);
  const int srow = t >> 3, sg8 = t & 7;

  const unsigned short* Ab = A + (size_t)(bm * 128) * K;
  const unsigned short* Bb = BT + (size_t)(bn * BN) * K;

  f32x4 acc[4][NF] = {};

  for (int kt = 0; kt < K; kt += 64) {
    __syncthreads();
    #pragma unroll
    for (int i = 0; i < 4; i++) {
      const int row = i * 32 + srow;
      const int g8 = sg8 ^ (row & 7);          // inverse source swizzle
      gl16(Ab + (size_t)row * K + kt + g8 * 8, &Alds[row * 64 + sg8 * 8]);
    }
    #pragma unroll
    for (int i = 0; i < BN / 32; i++) {
      const int row = i * 32 + srow;
      const int g8 = sg8 ^ (row & 7);
      gl16(Bb + (size_t)row * K + kt + g8 * 8, &Blds[row * 64 + sg8 * 8]);
    }
    __syncthreads();
    #pragma unroll
    for (int kc = 0; kc < 2; kc++) {
      bf16x8 af[4], bfr[NF];
      const int cofs = kc * 32 + lq * 8;
      const int swz = (lr & 7) * 8;
      #pragma unroll
      for (int i = 0; i < 4; i++)
        af[i]  = *reinterpret_cast<const bf16x8*>(&Alds[(wm + i * 16 + lr) * 64 + (cofs ^ swz)]);
      #pragma unroll
      for (int j = 0; j < NF; j++)
        bfr[j] = *reinterpret_cast<const bf16x8*>(&Blds[(wn + j * 16 + lr) * 64 + (cofs ^ swz)]);
      #pragma unroll
      for (int i = 0; i < 4; i++)
        #pragma unroll
        for (int j = 0; j < NF; j++)
          acc[i][j] = __builtin_amdgcn_mfma_f32_16x16x32_bf16(af[i], bfr[j], acc[i][j], 0, 0, 0);
    }
  }

  const int growbase = bm * 128 + wm + lq * 4;
  const int gcolbase = bn * BN + wn + lr;
  #pragma unroll
  for (int j = 0; j < NF; j++) {
    const int col = gcolbase + j * 16;
    const float bj = (MODE != 0) ? bias[col] : 0.f;
    #pragma unroll
    for (int i = 0; i < 4; i++) {
      #pragma unroll
      for (int r = 0; r < 4; r++) {
        const int grow = growbase + i * 16 + r;
        const float v = acc[i][j][r];
        if (MODE == 0) {
          ((unsigned short*)out)[(size_t)grow * N + col] = f2bf(v);
        } else if (MODE == 1 || MODE == 3) {
          ((float*)out)[(size_t)grow * N + col] = v + bj + resid[(size_t)grow * N + col];
        } else {
          const float u = v + bj;
          const float gel = 0.5f * u * (1.f + erff(u * 0.70710678118654752f));
          ((unsigned short*)out)[(size_t)grow * N + col] = f2bf(gel);
        }
      }
    }
  }
}

// ---------------- Flash attention v3 ----------------
// grid (S/128, H, B), 256 thr = 4 waves; wave owns 32 q-rows.
// Swapped QK^T (mfma(K,Q)) -> lane holds consecutive keys of one q-row.
// No-max softmax (c=0, shift-invariance); row-sum via ones-MFMA accumulator.
__global__ __launch_bounds__(256) void attn_kernel(
    const unsigned short* __restrict__ qkv,   // [8192][3072] (Q,K rope'd)
    const unsigned short* __restrict__ vt,    // [(b*16+h)*64 + d][2048]
    unsigned short* __restrict__ attout)      // [8192][1024]
{
  __shared__ unsigned short Ks[2][64 * 64];
  __shared__ unsigned short Vs[2][64 * 64];
  __shared__ unsigned short Ps[128 * 64];     // [q-local][key], XOR-swizzled
  const int qt = blockIdx.x, h = blockIdx.y, b = blockIdx.z;
  const int t = threadIdx.x, w = t >> 6, lane = t & 63;
  const int lq = lane >> 4, lr = lane & 15;
  const int srow = t >> 3, sg8 = t & 7;

  const unsigned short* kg = qkv + (size_t)(b * Ss_) * 3072 + 1024 + h * 64;
  const unsigned short* vg = vt + (size_t)((b * 16 + h) * 64) * Ss_;

  // Q fragments (used as MFMA B-operand: col=q=lr, k=d=kc*32+lq*8+j)
  bf16x8 aq[2][2];
  {
    const unsigned short* qg = qkv + (size_t)(b * Ss_ + qt * 128) * 3072 + h * 64;
    #pragma unroll
    for (int mt = 0; mt < 2; mt++)
      #pragma unroll
      for (int kc = 0; kc < 2; kc++)
        aq[mt][kc] = *reinterpret_cast<const bf16x8*>(
            qg + (size_t)(w * 32 + mt * 16 + lr) * 3072 + kc * 32 + lq * 8);
  }

  bf16x8 ones;
  #pragma unroll
  for (int j = 0; j < 8; j++) ones[j] = (__bf16)1.0f;

  f32x4 oacc[2][4] = {};
  f32x4 ssum[2] = {};   // row-sum accumulator (replicated over cols)

  const int g8s0 = sg8 ^ ((srow)      & 7);
  const int g8s1 = sg8 ^ ((srow + 32) & 7);

  // prologue: stage tile 0
  {
    gl16(kg + (size_t)(srow)      * 3072 + g8s0 * 8, &Ks[0][(srow)      * 64 + sg8 * 8]);
    gl16(kg + (size_t)(srow + 32) * 3072 + g8s1 * 8, &Ks[0][(srow + 32) * 64 + sg8 * 8]);
    gl16(vg + (size_t)(srow)      * Ss_  + g8s0 * 8, &Vs[0][(srow)      * 64 + sg8 * 8]);
    gl16(vg + (size_t)(srow + 32) * Ss_  + g8s1 * 8, &Vs[0][(srow + 32) * 64 + sg8 * 8]);
  }
  __syncthreads();

  const float SC2 = 0.125f * 1.44269504088896f;  // 1/sqrt(DH) * log2(e)

  for (int kt = 0; kt < Ss_ / 64; ++kt) {
    const int cur = kt & 1;
    if (kt < Ss_ / 64 - 1) {  // prefetch next tile into other buffer
      const int nb = cur ^ 1;
      const size_t ko = (size_t)((kt + 1) * 64);
      gl16(kg + (ko + srow)      * 3072 + g8s0 * 8, &Ks[nb][(srow)      * 64 + sg8 * 8]);
      gl16(kg + (ko + srow + 32) * 3072 + g8s1 * 8, &Ks[nb][(srow + 32) * 64 + sg8 * 8]);
      gl16(vg + (size_t)(srow)      * Ss_ + (kt + 1) * 64 + g8s0 * 8, &Vs[nb][(srow)      * 64 + sg8 * 8]);
      gl16(vg + (size_t)(srow + 32) * Ss_ + (kt + 1) * 64 + g8s1 * 8, &Vs[nb][(srow + 32) * 64 + sg8 * 8]);
    }

    // S^T = K Q^T : lane holds S[key=nf*16+lq*4+r][q=lr] for its wave's q-tiles
    f32x4 sacc[2][4] = {};
    #pragma unroll
    for (int kc = 0; kc < 2; kc++) {
      const int cofs = kc * 32 + lq * 8;
      const int swz = (lr & 7) * 8;
      bf16x8 kb[4];
      #pragma unroll
      for (int nf = 0; nf < 4; nf++)
        kb[nf] = *reinterpret_cast<const bf16x8*>(&Ks[cur][(nf * 16 + lr) * 64 + (cofs ^ swz)]);
      #pragma unroll
      for (int mt = 0; mt < 2; mt++)
        #pragma unroll
        for (int nf = 0; nf < 4; nf++)
          sacc[mt][nf] = __builtin_amdgcn_mfma_f32_16x16x32_bf16(kb[nf], aq[mt][kc], sacc[mt][nf], 0, 0, 0);
    }

    // P = exp2(S * SC2)  (no max subtraction; row-uniform shift c=0 is exact
    // for softmax, and scores are ~20 sigma below any overflow)
    #pragma unroll
    for (int mt = 0; mt < 2; mt++) {
      const int qrow = w * 32 + mt * 16 + lr;
      char* prow = reinterpret_cast<char*>(Ps) + qrow * 128;
      const int sw = (lr & 7) << 4;
      #pragma unroll
      for (int nf = 0; nf < 4; nf++) {
        const float p0 = __builtin_amdgcn_exp2f(sacc[mt][nf][0] * SC2);
        const float p1 = __builtin_amdgcn_exp2f(sacc[mt][nf][1] * SC2);
        const float p2 = __builtin_amdgcn_exp2f(sacc[mt][nf][2] * SC2);
        const float p3 = __builtin_amdgcn_exp2f(sacc[mt][nf][3] * SC2);
        uint2 pw;
        pw.x = cvt_pk_bf16(p0, p1);
        pw.y = cvt_pk_bf16(p2, p3);
        *reinterpret_cast<uint2*>(prow + ((nf * 32 + lq * 8) ^ sw)) = pw;
      }
    }

    // O += P V ; ssum += P * ones   (Ps rows are wave-local: no barrier)
    #pragma unroll
    for (int kc = 0; kc < 2; kc++) {
      const int cofs = kc * 32 + lq * 8;
      const int swz = (lr & 7) * 8;
      bf16x8 pa[2], vb[4];
      #pragma unroll
      for (int mt = 0; mt < 2; mt++) {
        const int qrow = w * 32 + mt * 16 + lr;
        pa[mt] = *reinterpret_cast<const bf16x8*>(
            reinterpret_cast<const char*>(Ps) + qrow * 128 + ((kc * 64 + lq * 16) ^ ((lr & 7) << 4)));
      }
      #pragma unroll
      for (int mt = 0; mt < 2; mt++)
        ssum[mt] = __builtin_amdgcn_mfma_f32_16x16x32_bf16(pa[mt], ones, ssum[mt], 0, 0, 0);
      #pragma unroll
      for (int nf = 0; nf < 4; nf++)
        vb[nf] = *reinterpret_cast<const bf16x8*>(&Vs[cur][(nf * 16 + lr) * 64 + (cofs ^ swz)]);
      #pragma unroll
      for (int mt = 0; mt < 2; mt++)
        #pragma unroll
        for (int nf = 0; nf < 4; nf++)
          oacc[mt][nf] = __builtin_amdgcn_mfma_f32_16x16x32_bf16(pa[mt], vb[nf], oacc[mt][nf], 0, 0, 0);
    }

    __syncthreads();  // all waves done with buf[cur]; prefetch drained
  }

  #pragma unroll
  for (int mt = 0; mt < 2; mt++) {
    #pragma unroll
    for (int r = 0; r < 4; r++) {
      const float inv = 1.f / ssum[mt][r];
      const int grow = b * Ss_ + qt * 128 + w * 32 + mt * 16 + lq * 4 + r;
      #pragma unroll
      for (int nf = 0; nf < 4; nf++)
        attout[(size_t)grow * Dd_ + h * 64 + nf * 16 + lr] = f2bf(oacc[mt][nf][r] * inv);
    }
  }
}

extern "C" void kernel_launch(void* const* d_in, const int* in_sizes, int n_in,
                              void* d_out, int out_size, void* d_ws, size_t ws_size,
                              hipStream_t stream) {
  const float* x      = (const float*)d_in[0];
  const float* fc     = (const float*)d_in[1];
  const float* wq     = (const float*)d_in[2];
  const float* wk     = (const float*)d_in[3];
  const float* wv     = (const float*)d_in[4];
  const float* w_proj = (const float*)d_in[5];
  const float* b_proj = (const float*)d_in[6];
  const float* w_ff1  = (const float*)d_in[7];
  const float* b_ff1  = (const float*)d_in[8];
  const float* w_ff2  = (const float*)d_in[9];
  const float* b_ff2  = (const float*)d_in[10];
  const float* ln1_g  = (const float*)d_in[11];
  const float* ln1_b  = (const float*)d_in[12];
  const float* ln2_g  = (const float*)d_in[13];
  const float* ln2_b  = (const float*)d_in[14];

  char* ws = (char*)d_ws;
  unsigned short* hb     = (unsigned short*)(ws);                  // 16 MB
  unsigned short* wqkvT  = (unsigned short*)(ws + 16777216ull);    // 6 MB
  unsigned short* wprojT = (unsigned short*)(ws + 23068672ull);    // 2 MB
  unsigned short* wff1T  = (unsigned short*)(ws + 25165824ull);    // 8 MB
  unsigned short* wff2T  = (unsigned short*)(ws + 33554432ull);    // 8 MB
  float*          x2     = (float*)(ws + 41943040ull);             // 32 MB (aliases vtb)
  unsigned short* vtb    = (unsigned short*)(ws + 41943040ull);    // 16 MB, dead before x2 written
  unsigned short* attoutb= (unsigned short*)(ws + 75497472ull);    // 16 MB
  unsigned short* qkvb   = (unsigned short*)(ws + 92274688ull);    // 64 MB (qkv then ff1)
  unsigned short* ff1b   = qkvb;

  dim3 blk(256);

  // weights -> bf16 transposed
  tconv_kernel<<<dim3(32, 32), blk, 0, stream>>>(wq, wqkvT, 1024, 1024);
  tconv_kernel<<<dim3(32, 32), blk, 0, stream>>>(wk, wqkvT + 1024 * 1024, 1024, 1024);
  tconv_kernel<<<dim3(32, 32), blk, 0, stream>>>(wv, wqkvT + 2 * 1024 * 1024, 1024, 1024);
  tconv_kernel<<<dim3(32, 32), blk, 0, stream>>>(w_proj, wprojT, 1024, 1024);
  tconv_kernel<<<dim3(128, 32), blk, 0, stream>>>(w_ff1, wff1T, 1024, 4096);
  tconv_kernel<<<dim3(32, 128), blk, 0, stream>>>(w_ff2, wff2T, 4096, 1024);

  // LN1
  ln_kernel<<<8192, blk, 0, stream>>>(x, ln1_g, ln1_b, hb);
  // QKV gemm (M=8192, N=3072, K=1024) -> bf16
  gemm_kernel<0, 128><<<dim3(24, 64), blk, 0, stream>>>(hb, wqkvT, 1024, 3072, nullptr, nullptr, qkvb);
  // RoPE on Q,K
  rope_kernel<<<8192, blk, 0, stream>>>(qkvb, fc);
  // V transpose -> vtb
  vtrans_kernel<<<dim3(32, 16, 4), blk, 0, stream>>>(qkvb, vtb);
  // attention
  attn_kernel<<<dim3(16, 16, 4), blk, 0, stream>>>(qkvb, vtb, attoutb);
  // proj + bias + residual -> x2 (f32)
  gemm_kernel<1, 64><<<dim3(16, 64), blk, 0, stream>>>(attoutb, wprojT, 1024, 1024, b_proj, x, x2);
  // LN2
  ln_kernel<<<8192, blk, 0, stream>>>(x2, ln2_g, ln2_b, hb);
  // FF1 + bias + gelu -> bf16
  gemm_kernel<2, 128><<<dim3(32, 64), blk, 0, stream>>>(hb, wff1T, 1024, 4096, b_ff1, nullptr, ff1b);
  // FF2 + bias + residual -> d_out (f32)
  gemm_kernel<3, 64><<<dim3(16, 64), blk, 0, stream>>>(ff1b, wff2T, 4096, 1024, b_ff2, x2, (float*)d_out);
}